// Round 1
// 1067.203 us; speedup vs baseline: 1.0436x; 1.0436x over previous
//
#include <hip/hip_runtime.h>

// ---------------------------------------------------------------------------
// 3-layer GraphSAGE forward, R3: fused marshalling.
//   - mfma_gemm2 is dual-source: self half read in place (fp32 x for L0 with
//     in-flight bf16 convert; bf16 h for L1/L2), neigh half from compact mean
//     buffer nb[dst][Kneigh]. Eliminates cvt_self0 + copy_self passes.
//   - CSR build (hist/offsets/build) merged across the 3 layers (segment
//     boundaries all multiples of 256 -> block-uniform segments).
//   - prep_w merged into one launch.
// 11 dispatches total (was 19).
// ---------------------------------------------------------------------------

constexpr int kN1 = 262144;
constexpr int kN2 = 32768;
constexpr int kN3 = 8192;
constexpr int kE0 = 1310720;
constexpr int kE1 = 327680;
constexpr int kE2 = 81920;

typedef __attribute__((ext_vector_type(8))) short short8;
typedef __attribute__((ext_vector_type(4))) float floatx4;

static inline unsigned cdiv_u(long long a, long long b) { return (unsigned)((a + b - 1) / b); }

__device__ __forceinline__ unsigned short f2bf(float f) {
  union { float f; unsigned u; } v; v.f = f;
  return (unsigned short)((v.u + 0x7fffu + ((v.u >> 16) & 1u)) >> 16);
}
__device__ __forceinline__ float blo(unsigned u) {
  union { unsigned u; float f; } v; v.u = u << 16; return v.f;
}
__device__ __forceinline__ float bhi(unsigned u) {
  union { unsigned u; float f; } v; v.u = u & 0xffff0000u; return v.f;
}

// ---- merged histogram over all 3 edge lists ----
__global__ __launch_bounds__(256) void hist3_kernel(
    const int* __restrict__ d0, int* __restrict__ c0,
    const int* __restrict__ d1, int* __restrict__ c1,
    const int* __restrict__ d2, int* __restrict__ c2) {
  int e = blockIdx.x * 256 + threadIdx.x;
  if (e < kE0) {
    atomicAdd(&c0[d0[e]], 1);
  } else if (e < kE0 + kE1) {
    atomicAdd(&c1[d1[e - kE0]], 1);
  } else {
    atomicAdd(&c2[d2[e - kE0 - kE1]], 1);
  }
}

// ---- merged exclusive-offset build (wave scan + global atomic base) ----
__global__ __launch_bounds__(256) void offsets3_kernel(
    const int* __restrict__ c0, int* __restrict__ o0, int* __restrict__ u0,
    const int* __restrict__ c1, int* __restrict__ o1, int* __restrict__ u1,
    const int* __restrict__ c2, int* __restrict__ o2, int* __restrict__ u2,
    int* __restrict__ gctr) {
  int i = blockIdx.x * 256 + threadIdx.x;  // grid covers exactly N1+N2+N3
  const int* cnt; int* off; int* cur; int* g; int local;
  if (i < kN1) {
    cnt = c0; off = o0; cur = u0; g = gctr + 0; local = i;
  } else if (i < kN1 + kN2) {
    cnt = c1; off = o1; cur = u1; g = gctr + 1; local = i - kN1;
  } else {
    cnt = c2; off = o2; cur = u2; g = gctr + 2; local = i - kN1 - kN2;
  }
  int lane = threadIdx.x & 63;
  int c = cnt[local];
  int v = c;
#pragma unroll
  for (int d = 1; d < 64; d <<= 1) {
    int u = __shfl_up(v, d);
    if (lane >= d) v += u;
  }
  int waveTotal = __shfl(v, 63);
  int base = 0;
  if (lane == 63) base = atomicAdd(g, waveTotal);
  base = __shfl(base, 63);
  int excl = base + v - c;
  off[local] = excl;
  cur[local] = excl;
}

// ---- merged CSR scatter ----
__global__ __launch_bounds__(256) void build3_kernel(
    const int* __restrict__ s0, const int* __restrict__ d0, int* __restrict__ u0, int* __restrict__ x0,
    const int* __restrict__ s1, const int* __restrict__ d1, int* __restrict__ u1, int* __restrict__ x1,
    const int* __restrict__ s2, const int* __restrict__ d2, int* __restrict__ u2, int* __restrict__ x2) {
  int e = blockIdx.x * 256 + threadIdx.x;
  const int *src, *dst; int *cur, *eidx; int le;
  if (e < kE0) {
    src = s0; dst = d0; cur = u0; eidx = x0; le = e;
  } else if (e < kE0 + kE1) {
    src = s1; dst = d1; cur = u1; eidx = x1; le = e - kE0;
  } else {
    src = s2; dst = d2; cur = u2; eidx = x2; le = e - kE0 - kE1;
  }
  int p = atomicAdd(&cur[dst[le]], 1);
  eidx[p] = src[le];
}

// ---- weight prep: Wt[n][k] bf16, [Ws rows @ k<Kself | Wn rows @ KnOff..] ----
__device__ __forceinline__ void prep_one(
    const float* __restrict__ Ws, const float* __restrict__ Wn,
    unsigned short* __restrict__ Wt, int Kself, int KnOff, int Kneigh,
    int Ktot, int Nsrc, int t) {
  int n = t / Ktot, k = t - n * Ktot;
  float v = 0.f;
  if (n < Nsrc) {
    if (k < Kself) v = Ws[(size_t)k * Nsrc + n];
    else {
      int kk = k - KnOff;
      if (kk >= 0 && kk < Kneigh) v = Wn[(size_t)kk * Nsrc + n];
    }
  }
  Wt[(size_t)n * Ktot + k] = f2bf(v);
}

__global__ __launch_bounds__(256) void prep_w3_kernel(
    const float* __restrict__ Ws0, const float* __restrict__ Wn0, unsigned short* __restrict__ Wt0,
    const float* __restrict__ Ws1, const float* __restrict__ Wn1, unsigned short* __restrict__ Wt1,
    const float* __restrict__ Ws2, const float* __restrict__ Wn2, unsigned short* __restrict__ Wt2) {
  int t = blockIdx.x * 256 + threadIdx.x;  // grid covers exactly 65536+131072+131072
  if (t < 65536) prep_one(Ws0, Wn0, Wt0, 100, 128, 100, 256, 256, t);
  else if (t < 65536 + 131072) prep_one(Ws1, Wn1, Wt1, 256, 256, 256, 512, 256, t - 65536);
  else prep_one(Ws2, Wn2, Wt2, 256, 256, 256, 512, 47, t - 196608);
}

// ---- gather mean, fp32 source (layer 0) -> nb0[dst][128] bf16 (cols>=100 zero) ----
__global__ __launch_bounds__(256) void gather_mean0(
    const int* __restrict__ off, const int* __restrict__ cnt,
    const int* __restrict__ eidx, const float* __restrict__ x,
    unsigned short* __restrict__ nb, int nDst) {
  int t = blockIdx.x * 256 + threadIdx.x;
  int d = t >> 5, c = t & 31;
  if (d >= nDst) return;
  unsigned short* dst = nb + (size_t)d * 128 + c * 4;
  if (c >= 25) { uint2 z; z.x = 0; z.y = 0; *(uint2*)dst = z; return; }
  int o = off[d], n = cnt[d];
  float ax = 0.f, ay = 0.f, az = 0.f, aw = 0.f;
  const float* xc = x + c * 4;
  for (int i = 0; i < n; ++i) {
    int s = eidx[o + i];
    float4 v = *(const float4*)(xc + (size_t)s * 100);
    ax += v.x; ay += v.y; az += v.z; aw += v.w;
  }
  float inv = 1.0f / fmaxf((float)n, 1.0f);
  uint2 pk;
  pk.x = (unsigned)f2bf(ax * inv) | ((unsigned)f2bf(ay * inv) << 16);
  pk.y = (unsigned)f2bf(az * inv) | ((unsigned)f2bf(aw * inv) << 16);
  *(uint2*)dst = pk;
}

// ---- gather mean, bf16 source [*,256] -> nb[dst][256] bf16 ----
__global__ __launch_bounds__(256) void gather_mean_bf(
    const int* __restrict__ off, const int* __restrict__ cnt,
    const int* __restrict__ eidx, const unsigned short* __restrict__ h,
    unsigned short* __restrict__ nb, int nDst) {
  int t = blockIdx.x * 256 + threadIdx.x;
  int d = t >> 5, c = t & 31;
  if (d >= nDst) return;
  int o = off[d], n = cnt[d];
  float acc[8];
#pragma unroll
  for (int u = 0; u < 8; ++u) acc[u] = 0.f;
  const unsigned short* hc = h + c * 8;
  for (int i = 0; i < n; ++i) {
    int s = eidx[o + i];
    uint4 v = *(const uint4*)(hc + (size_t)s * 256);
    acc[0] += blo(v.x); acc[1] += bhi(v.x);
    acc[2] += blo(v.y); acc[3] += bhi(v.y);
    acc[4] += blo(v.z); acc[5] += bhi(v.z);
    acc[6] += blo(v.w); acc[7] += bhi(v.w);
  }
  float inv = 1.0f / fmaxf((float)n, 1.0f);
  uint4 pk;
  pk.x = (unsigned)f2bf(acc[0] * inv) | ((unsigned)f2bf(acc[1] * inv) << 16);
  pk.y = (unsigned)f2bf(acc[2] * inv) | ((unsigned)f2bf(acc[3] * inv) << 16);
  pk.z = (unsigned)f2bf(acc[4] * inv) | ((unsigned)f2bf(acc[5] * inv) << 16);
  pk.w = (unsigned)f2bf(acc[6] * inv) | ((unsigned)f2bf(acc[7] * inv) << 16);
  *(uint4*)(nb + (size_t)d * 256 + c * 8) = pk;
}

// ---- dual-source MFMA GEMM: C[M,256] = [self | neigh] @ Wt[256,KT]^T (+b, relu)
// Block 256 = 4 waves; BM=64, BN=256 (full N). Wave w: n in [w*64, w*64+64).
// k < KSELF : staged from Aself in place (fp32 x w/ convert if SELF_F32,
//             else bf16 h, stride selfStride elements).
// k >= KSELF: staged from Aneigh[row][KNEIGH] bf16.
// LDS rows padded 32->40 ushorts (2-way bank conflict = free).
template <int KSELF, int KNEIGH, bool SELF_F32, bool RELU, bool OUT_BF16>
__global__ __launch_bounds__(256) void mfma_gemm2(
    const void* __restrict__ AselfV, int selfStride,
    const unsigned short* __restrict__ Aneigh,
    const unsigned short* __restrict__ Wt,
    const float* __restrict__ bias, void* __restrict__ out, int nstore) {
  constexpr int KT = KSELF + KNEIGH;
  __shared__ __align__(16) unsigned short As[64 * 40];
  __shared__ __align__(16) unsigned short Bs[256 * 40];
  const int tid = threadIdx.x;
  const int lane = tid & 63, w = tid >> 6;
  const int q = lane >> 4, l15 = lane & 15;
  const size_t row0 = (size_t)blockIdx.x * 64;

  const int arow = tid >> 2, ac8 = (tid & 3) * 8;
  const size_t grow = row0 + arow;

  floatx4 acc[4][4];
#pragma unroll
  for (int i = 0; i < 4; ++i)
#pragma unroll
    for (int j = 0; j < 4; ++j) acc[i][j] = (floatx4){0.f, 0.f, 0.f, 0.f};

  for (int k0 = 0; k0 < KT; k0 += 32) {
    __syncthreads();
    uint4 pk;
    if (k0 < KSELF) {
      int k = k0 + ac8;
      if (SELF_F32) {
        // fp32 source, real cols < selfStride (=100), convert in flight.
        const float* p = (const float*)AselfV + grow * (size_t)selfStride + k;
        float4 v0 = make_float4(0.f, 0.f, 0.f, 0.f);
        float4 v1 = make_float4(0.f, 0.f, 0.f, 0.f);
        if (k < selfStride) v0 = *(const float4*)p;            // k mult of 8, k<100 => k<=96, k+3<=99 ok
        if (k + 4 < selfStride) v1 = *(const float4*)(p + 4);  // k<=92
        pk.x = (unsigned)f2bf(v0.x) | ((unsigned)f2bf(v0.y) << 16);
        pk.y = (unsigned)f2bf(v0.z) | ((unsigned)f2bf(v0.w) << 16);
        pk.z = (unsigned)f2bf(v1.x) | ((unsigned)f2bf(v1.y) << 16);
        pk.w = (unsigned)f2bf(v1.z) | ((unsigned)f2bf(v1.w) << 16);
      } else {
        pk = *(const uint4*)((const unsigned short*)AselfV + grow * (size_t)selfStride + k);
      }
    } else {
      int k = k0 - KSELF + ac8;
      pk = *(const uint4*)(Aneigh + grow * (size_t)KNEIGH + k);
    }
    *(uint4*)&As[arow * 40 + ac8] = pk;
#pragma unroll
    for (int it = 0; it < 4; ++it) {
      int g = tid + it * 256;
      int brow = g >> 2, bk8 = (g & 3) * 8;
      *(uint4*)&Bs[brow * 40 + bk8] = *(const uint4*)&Wt[(size_t)brow * KT + k0 + bk8];
    }
    __syncthreads();
    short8 af[4], bfv[4];
#pragma unroll
    for (int i = 0; i < 4; ++i)
      af[i] = *(const short8*)&As[(i * 16 + l15) * 40 + q * 8];
#pragma unroll
    for (int j = 0; j < 4; ++j)
      bfv[j] = *(const short8*)&Bs[(w * 64 + j * 16 + l15) * 40 + q * 8];
#pragma unroll
    for (int i = 0; i < 4; ++i)
#pragma unroll
      for (int j = 0; j < 4; ++j)
        acc[i][j] = __builtin_amdgcn_mfma_f32_16x16x32_bf16(af[i], bfv[j], acc[i][j], 0, 0, 0);
  }

  float bj[4];
#pragma unroll
  for (int j = 0; j < 4; ++j) {
    int col = w * 64 + j * 16 + l15;
    bj[j] = (col < nstore) ? bias[col] : 0.f;
  }
#pragma unroll
  for (int i = 0; i < 4; ++i) {
#pragma unroll
    for (int reg = 0; reg < 4; ++reg) {
      size_t row = row0 + i * 16 + q * 4 + reg;
#pragma unroll
      for (int j = 0; j < 4; ++j) {
        int col = w * 64 + j * 16 + l15;
        float v = acc[i][j][reg] + bj[j];
        if (RELU) v = fmaxf(v, 0.f);
        if (OUT_BF16) {
          ((unsigned short*)out)[row * 256 + col] = f2bf(v);
        } else if (col < nstore) {
          ((float*)out)[row * (size_t)nstore + col] = v;
        }
      }
    }
  }
}

extern "C" void kernel_launch(void* const* d_in, const int* in_sizes, int n_in,
                              void* d_out, int out_size, void* d_ws, size_t ws_size,
                              hipStream_t stream) {
  const float* x   = (const float*)d_in[0];
  const int* es0   = (const int*)d_in[1];
  const int* ed0   = (const int*)d_in[2];
  const int* es1   = (const int*)d_in[3];
  const int* ed1   = (const int*)d_in[4];
  const int* es2   = (const int*)d_in[5];
  const int* ed2   = (const int*)d_in[6];
  const float* Ws0 = (const float*)d_in[7];
  const float* Wn0 = (const float*)d_in[8];
  const float* b0  = (const float*)d_in[9];
  const float* Ws1 = (const float*)d_in[10];
  const float* Wn1 = (const float*)d_in[11];
  const float* b1  = (const float*)d_in[12];
  const float* Ws2 = (const float*)d_in[13];
  const float* Wn2 = (const float*)d_in[14];
  const float* b2  = (const float*)d_in[15];
  float* out = (float*)d_out;

  // ---- workspace layout (disjoint, ~250 MB) ----
  char* ws = (char*)d_ws;
  unsigned short* h1b  = (unsigned short*)(ws + 0ull);          // 262144*256*2 = 134,217,728
  unsigned short* h2b  = (unsigned short*)(ws + 134217728ull);  //  32768*256*2 =  16,777,216
  unsigned short* nb0  = (unsigned short*)(ws + 150994944ull);  // 262144*128*2 =  67,108,864
  unsigned short* nb1  = (unsigned short*)(ws + 218103808ull);  //  32768*256*2 =  16,777,216
  unsigned short* nb2  = (unsigned short*)(ws + 234881024ull);  //   8192*256*2 =   4,194,304
  unsigned short* Wt0  = (unsigned short*)(ws + 239075328ull);  //     131,072
  unsigned short* Wt1  = (unsigned short*)(ws + 239206400ull);  //     262,144
  unsigned short* Wt2  = (unsigned short*)(ws + 239468544ull);  //     262,144
  int* cnt0 = (int*)(ws + 239730688ull);   // 1,048,576
  int* cnt1 = (int*)(ws + 240779264ull);   //   131,072
  int* cnt2 = (int*)(ws + 240910336ull);   //    32,768
  int* gctr = (int*)(ws + 240943104ull);   //       256
  int* off0 = (int*)(ws + 240943360ull);   // 1,048,576
  int* off1 = (int*)(ws + 241991936ull);   //   131,072
  int* off2 = (int*)(ws + 242123008ull);   //    32,768
  int* cur0 = (int*)(ws + 242155776ull);   // 1,048,576
  int* cur1 = (int*)(ws + 243204352ull);   //   131,072
  int* cur2 = (int*)(ws + 243335424ull);   //    32,768
  int* eidx0 = (int*)(ws + 243368192ull);  // 5,242,880
  int* eidx1 = (int*)(ws + 248611072ull);  // 1,310,720
  int* eidx2 = (int*)(ws + 249921792ull);  //   327,680

  // zero cnt0|cnt1|cnt2|gctr in one contiguous span [239730688, 240943360)
  hipMemsetAsync(ws + 239730688ull, 0, 1212672ull, stream);

  // ---- CSR builds, merged across layers (3 launches) ----
  hist3_kernel<<<cdiv_u(kE0 + kE1 + kE2, 256), 256, 0, stream>>>(
      ed0, cnt0, ed1, cnt1, ed2, cnt2);
  offsets3_kernel<<<cdiv_u(kN1 + kN2 + kN3, 256), 256, 0, stream>>>(
      cnt0, off0, cur0, cnt1, off1, cur1, cnt2, off2, cur2, gctr);
  build3_kernel<<<cdiv_u(kE0 + kE1 + kE2, 256), 256, 0, stream>>>(
      es0, ed0, cur0, eidx0, es1, ed1, cur1, eidx1, es2, ed2, cur2, eidx2);

  // ---- weight prep (1 launch) ----
  prep_w3_kernel<<<cdiv_u(65536 + 131072 + 131072, 256), 256, 0, stream>>>(
      Ws0, Wn0, Wt0, Ws1, Wn1, Wt1, Ws2, Wn2, Wt2);

  // ---- layer 0: gather -> nb0; GEMM reads self straight from x (fp32) ----
  gather_mean0<<<cdiv_u((long long)kN1 * 32, 256), 256, 0, stream>>>(
      off0, cnt0, eidx0, x, nb0, kN1);
  mfma_gemm2<128, 128, true, true, true><<<kN1 / 64, 256, 0, stream>>>(
      x, 100, nb0, Wt0, b0, h1b, 256);

  // ---- layer 1: gather -> nb1; GEMM reads self straight from h1b ----
  gather_mean_bf<<<cdiv_u((long long)kN2 * 32, 256), 256, 0, stream>>>(
      off1, cnt1, eidx1, h1b, nb1, kN2);
  mfma_gemm2<256, 256, false, true, true><<<kN2 / 64, 256, 0, stream>>>(
      h1b, 256, nb1, Wt1, b1, h2b, 256);

  // ---- layer 2: gather -> nb2; GEMM reads self straight from h2b ----
  gather_mean_bf<<<cdiv_u((long long)kN3 * 32, 256), 256, 0, stream>>>(
      off2, cnt2, eidx2, h2b, nb2, kN3);
  mfma_gemm2<256, 256, false, false, false><<<kN3 / 64, 256, 0, stream>>>(
      h2b, 256, nb2, Wt2, b2, out, 47);
}

// Round 2
// 1034.849 us; speedup vs baseline: 1.0762x; 1.0313x over previous
//
#include <hip/hip_runtime.h>

// ---------------------------------------------------------------------------
// 3-layer GraphSAGE forward, R4: gather fused into GEMM.
//   - sage_gemm does the neighbor gather-mean as a register-resident prologue
//     (4 threads/row, 8-col chunks == the A-staging decomposition), then runs
//     the dual-source MFMA K-loop with the neigh half sourced from registers.
//     Eliminates nb* buffers entirely (176 MB HBM round-trip) and 3 launches.
//   - prep_w folded into the hist launch.
// 7 dispatches total (was 11).
// ---------------------------------------------------------------------------

constexpr int kN1 = 262144;
constexpr int kN2 = 32768;
constexpr int kN3 = 8192;
constexpr int kE0 = 1310720;
constexpr int kE1 = 327680;
constexpr int kE2 = 81920;

typedef __attribute__((ext_vector_type(8))) short short8;
typedef __attribute__((ext_vector_type(4))) float floatx4;

static inline unsigned cdiv_u(long long a, long long b) { return (unsigned)((a + b - 1) / b); }

__device__ __forceinline__ unsigned short f2bf(float f) {
  union { float f; unsigned u; } v; v.f = f;
  return (unsigned short)((v.u + 0x7fffu + ((v.u >> 16) & 1u)) >> 16);
}
__device__ __forceinline__ float blo(unsigned u) {
  union { unsigned u; float f; } v; v.u = u << 16; return v.f;
}
__device__ __forceinline__ float bhi(unsigned u) {
  union { unsigned u; float f; } v; v.u = u & 0xffff0000u; return v.f;
}

// ---- weight prep helper: Wt[n][k] bf16, [Ws rows @ k<Kself | Wn @ KnOff..] ----
__device__ __forceinline__ void prep_one(
    const float* __restrict__ Ws, const float* __restrict__ Wn,
    unsigned short* __restrict__ Wt, int Kself, int KnOff, int Kneigh,
    int Ktot, int Nsrc, int t) {
  int n = t / Ktot, k = t - n * Ktot;
  float v = 0.f;
  if (n < Nsrc) {
    if (k < Kself) v = Ws[(size_t)k * Nsrc + n];
    else {
      int kk = k - KnOff;
      if (kk >= 0 && kk < Kneigh) v = Wn[(size_t)kk * Nsrc + n];
    }
  }
  Wt[(size_t)n * Ktot + k] = f2bf(v);
}

// ---- merged histogram over all 3 edge lists + weight prep (independent) ----
// grid: [0, 6720) histogram blocks, [6720, 8000) weight-prep blocks.
__global__ __launch_bounds__(256) void hist3_prep_kernel(
    const int* __restrict__ d0, int* __restrict__ c0,
    const int* __restrict__ d1, int* __restrict__ c1,
    const int* __restrict__ d2, int* __restrict__ c2,
    const float* __restrict__ Ws0, const float* __restrict__ Wn0, unsigned short* __restrict__ Wt0,
    const float* __restrict__ Ws1, const float* __restrict__ Wn1, unsigned short* __restrict__ Wt1,
    const float* __restrict__ Ws2, const float* __restrict__ Wn2, unsigned short* __restrict__ Wt2) {
  int b = blockIdx.x;
  if (b < 6720) {
    int e = b * 256 + threadIdx.x;
    if (e < kE0) {
      atomicAdd(&c0[d0[e]], 1);
    } else if (e < kE0 + kE1) {
      atomicAdd(&c1[d1[e - kE0]], 1);
    } else {
      atomicAdd(&c2[d2[e - kE0 - kE1]], 1);
    }
  } else {
    int t = (b - 6720) * 256 + threadIdx.x;  // [0, 327680)
    if (t < 65536) prep_one(Ws0, Wn0, Wt0, 100, 128, 100, 256, 256, t);
    else if (t < 65536 + 131072) prep_one(Ws1, Wn1, Wt1, 256, 256, 256, 512, 256, t - 65536);
    else prep_one(Ws2, Wn2, Wt2, 256, 256, 256, 512, 47, t - 196608);
  }
}

// ---- merged exclusive-offset build (wave scan + global atomic base) ----
__global__ __launch_bounds__(256) void offsets3_kernel(
    const int* __restrict__ c0, int* __restrict__ o0, int* __restrict__ u0,
    const int* __restrict__ c1, int* __restrict__ o1, int* __restrict__ u1,
    const int* __restrict__ c2, int* __restrict__ o2, int* __restrict__ u2,
    int* __restrict__ gctr) {
  int i = blockIdx.x * 256 + threadIdx.x;  // grid covers exactly N1+N2+N3
  const int* cnt; int* off; int* cur; int* g; int local;
  if (i < kN1) {
    cnt = c0; off = o0; cur = u0; g = gctr + 0; local = i;
  } else if (i < kN1 + kN2) {
    cnt = c1; off = o1; cur = u1; g = gctr + 1; local = i - kN1;
  } else {
    cnt = c2; off = o2; cur = u2; g = gctr + 2; local = i - kN1 - kN2;
  }
  int lane = threadIdx.x & 63;
  int c = cnt[local];
  int v = c;
#pragma unroll
  for (int d = 1; d < 64; d <<= 1) {
    int u = __shfl_up(v, d);
    if (lane >= d) v += u;
  }
  int waveTotal = __shfl(v, 63);
  int base = 0;
  if (lane == 63) base = atomicAdd(g, waveTotal);
  base = __shfl(base, 63);
  int excl = base + v - c;
  off[local] = excl;
  cur[local] = excl;
}

// ---- merged CSR scatter ----
__global__ __launch_bounds__(256) void build3_kernel(
    const int* __restrict__ s0, const int* __restrict__ d0, int* __restrict__ u0, int* __restrict__ x0,
    const int* __restrict__ s1, const int* __restrict__ d1, int* __restrict__ u1, int* __restrict__ x1,
    const int* __restrict__ s2, const int* __restrict__ d2, int* __restrict__ u2, int* __restrict__ x2) {
  int e = blockIdx.x * 256 + threadIdx.x;
  const int *src, *dst; int *cur, *eidx; int le;
  if (e < kE0) {
    src = s0; dst = d0; cur = u0; eidx = x0; le = e;
  } else if (e < kE0 + kE1) {
    src = s1; dst = d1; cur = u1; eidx = x1; le = e - kE0;
  } else {
    src = s2; dst = d2; cur = u2; eidx = x2; le = e - kE0 - kE1;
  }
  int p = atomicAdd(&cur[dst[le]], 1);
  eidx[p] = src[le];
}

// ---------------------------------------------------------------------------
// Fused gather-mean + dual-source MFMA GEMM.
//   C[M,256] = relu( [self | neigh_mean] @ Wt[256,KT]^T + b )
// Block 256 = 4 waves; BM=64, BN=256 (full N). Wave w: n in [w*64, w*64+64).
// Prologue: thread (r=tid>>2, cquad=tid&3) accumulates neigh-mean for row r,
//   cols {cquad*8 + 32*i | i<NI} in fp32 regs, packs to bf16 held[NI].
//   (Exactly the A-staging decomposition, so the K-loop can source As from
//    held[] for k0 >= KSELF with zero extra LDS.)
// K-loop: k0 < KSELF staged from Aself in place (fp32 x w/ convert if
//   SELF_F32, else bf16 h); k0 >= KSELF from held[]. #pragma unroll keeps
//   held[] statically indexed (no scratch).
// LDS rows padded 32->40 ushorts (2-way bank conflict = free).
// ---------------------------------------------------------------------------
template <int KSELF, int KNEIGH, bool SELF_F32, bool RELU, bool OUT_BF16>
__global__ __launch_bounds__(256) void sage_gemm(
    const void* __restrict__ AselfV, int selfStride,
    const int* __restrict__ off, const int* __restrict__ cnt,
    const int* __restrict__ eidx, const void* __restrict__ SrcV,
    const unsigned short* __restrict__ Wt,
    const float* __restrict__ bias, void* __restrict__ out, int nstore) {
  constexpr int KT = KSELF + KNEIGH;
  constexpr int NI = KNEIGH / 32;
  __shared__ __align__(16) unsigned short As[64 * 40];
  __shared__ __align__(16) unsigned short Bs[256 * 40];
  const int tid = threadIdx.x;
  const int lane = tid & 63, w = tid >> 6;
  const int q = lane >> 4, l15 = lane & 15;
  const size_t row0 = (size_t)blockIdx.x * 64;
  const int arow = tid >> 2, ac8 = (tid & 3) * 8;
  const size_t grow = row0 + arow;

  // ---- phase 1: gather-mean neigh half into registers ----
  uint4 held[NI];
  {
    int o = off[grow], n = cnt[grow];
    float ga[NI * 8];
#pragma unroll
    for (int u = 0; u < NI * 8; ++u) ga[u] = 0.f;
    if constexpr (SELF_F32) {
      const float* xs = (const float*)SrcV;
      for (int e = 0; e < n; ++e) {
        int s = eidx[o + e];
        const float* p = xs + (size_t)s * selfStride + ac8;
#pragma unroll
        for (int i = 0; i < NI; ++i) {
          int c = ac8 + 32 * i;
          if (c < 100) {  // c multiple of 8: c<=96; [c,c+3] valid
            float4 a = *(const float4*)(p + 32 * i);
            ga[i * 8 + 0] += a.x; ga[i * 8 + 1] += a.y;
            ga[i * 8 + 2] += a.z; ga[i * 8 + 3] += a.w;
            if (c + 4 < 100) {  // c<=92: [c+4,c+7] valid
              float4 b = *(const float4*)(p + 32 * i + 4);
              ga[i * 8 + 4] += b.x; ga[i * 8 + 5] += b.y;
              ga[i * 8 + 6] += b.z; ga[i * 8 + 7] += b.w;
            }
          }
        }
      }
    } else {
      const unsigned short* hs = (const unsigned short*)SrcV;
      for (int e = 0; e < n; ++e) {
        int s = eidx[o + e];
        const unsigned short* p = hs + (size_t)s * 256 + ac8;
#pragma unroll
        for (int i = 0; i < NI; ++i) {
          uint4 v = *(const uint4*)(p + 32 * i);
          ga[i * 8 + 0] += blo(v.x); ga[i * 8 + 1] += bhi(v.x);
          ga[i * 8 + 2] += blo(v.y); ga[i * 8 + 3] += bhi(v.y);
          ga[i * 8 + 4] += blo(v.z); ga[i * 8 + 5] += bhi(v.z);
          ga[i * 8 + 6] += blo(v.w); ga[i * 8 + 7] += bhi(v.w);
        }
      }
    }
    float inv = 1.0f / fmaxf((float)n, 1.0f);
#pragma unroll
    for (int i = 0; i < NI; ++i) {
      uint4 pk;
      pk.x = (unsigned)f2bf(ga[i * 8 + 0] * inv) | ((unsigned)f2bf(ga[i * 8 + 1] * inv) << 16);
      pk.y = (unsigned)f2bf(ga[i * 8 + 2] * inv) | ((unsigned)f2bf(ga[i * 8 + 3] * inv) << 16);
      pk.z = (unsigned)f2bf(ga[i * 8 + 4] * inv) | ((unsigned)f2bf(ga[i * 8 + 5] * inv) << 16);
      pk.w = (unsigned)f2bf(ga[i * 8 + 6] * inv) | ((unsigned)f2bf(ga[i * 8 + 7] * inv) << 16);
      held[i] = pk;
    }
  }

  // ---- phase 2: MFMA K-loop ----
  floatx4 acc[4][4];
#pragma unroll
  for (int i = 0; i < 4; ++i)
#pragma unroll
    for (int j = 0; j < 4; ++j) acc[i][j] = (floatx4){0.f, 0.f, 0.f, 0.f};

#pragma unroll
  for (int k0 = 0; k0 < KT; k0 += 32) {
    __syncthreads();
    uint4 pk;
    if (k0 < KSELF) {
      int k = k0 + ac8;
      if constexpr (SELF_F32) {
        const float* p = (const float*)AselfV + grow * (size_t)selfStride + k;
        float4 v0 = make_float4(0.f, 0.f, 0.f, 0.f);
        float4 v1 = make_float4(0.f, 0.f, 0.f, 0.f);
        if (k < selfStride) v0 = *(const float4*)p;
        if (k + 4 < selfStride) v1 = *(const float4*)(p + 4);
        pk.x = (unsigned)f2bf(v0.x) | ((unsigned)f2bf(v0.y) << 16);
        pk.y = (unsigned)f2bf(v0.z) | ((unsigned)f2bf(v0.w) << 16);
        pk.z = (unsigned)f2bf(v1.x) | ((unsigned)f2bf(v1.y) << 16);
        pk.w = (unsigned)f2bf(v1.z) | ((unsigned)f2bf(v1.w) << 16);
      } else {
        pk = *(const uint4*)((const unsigned short*)AselfV + grow * (size_t)selfStride + k);
      }
    } else {
      pk = held[(k0 - KSELF) / 32];  // static after unroll
    }
    *(uint4*)&As[arow * 40 + ac8] = pk;
#pragma unroll
    for (int it = 0; it < 4; ++it) {
      int g = tid + it * 256;
      int brow = g >> 2, bk8 = (g & 3) * 8;
      *(uint4*)&Bs[brow * 40 + bk8] = *(const uint4*)&Wt[(size_t)brow * KT + k0 + bk8];
    }
    __syncthreads();
    short8 af[4], bfv[4];
#pragma unroll
    for (int i = 0; i < 4; ++i)
      af[i] = *(const short8*)&As[(i * 16 + l15) * 40 + q * 8];
#pragma unroll
    for (int j = 0; j < 4; ++j)
      bfv[j] = *(const short8*)&Bs[(w * 64 + j * 16 + l15) * 40 + q * 8];
#pragma unroll
    for (int i = 0; i < 4; ++i)
#pragma unroll
      for (int j = 0; j < 4; ++j)
        acc[i][j] = __builtin_amdgcn_mfma_f32_16x16x32_bf16(af[i], bfv[j], acc[i][j], 0, 0, 0);
  }

  float bj[4];
#pragma unroll
  for (int j = 0; j < 4; ++j) {
    int col = w * 64 + j * 16 + l15;
    bj[j] = (col < nstore) ? bias[col] : 0.f;
  }
#pragma unroll
  for (int i = 0; i < 4; ++i) {
#pragma unroll
    for (int reg = 0; reg < 4; ++reg) {
      size_t row = row0 + i * 16 + q * 4 + reg;
#pragma unroll
      for (int j = 0; j < 4; ++j) {
        int col = w * 64 + j * 16 + l15;
        float v = acc[i][j][reg] + bj[j];
        if (RELU) v = fmaxf(v, 0.f);
        if (OUT_BF16) {
          ((unsigned short*)out)[row * 256 + col] = f2bf(v);
        } else if (col < nstore) {
          ((float*)out)[row * (size_t)nstore + col] = v;
        }
      }
    }
  }
}

extern "C" void kernel_launch(void* const* d_in, const int* in_sizes, int n_in,
                              void* d_out, int out_size, void* d_ws, size_t ws_size,
                              hipStream_t stream) {
  const float* x   = (const float*)d_in[0];
  const int* es0   = (const int*)d_in[1];
  const int* ed0   = (const int*)d_in[2];
  const int* es1   = (const int*)d_in[3];
  const int* ed1   = (const int*)d_in[4];
  const int* es2   = (const int*)d_in[5];
  const int* ed2   = (const int*)d_in[6];
  const float* Ws0 = (const float*)d_in[7];
  const float* Wn0 = (const float*)d_in[8];
  const float* b0  = (const float*)d_in[9];
  const float* Ws1 = (const float*)d_in[10];
  const float* Wn1 = (const float*)d_in[11];
  const float* b1  = (const float*)d_in[12];
  const float* Ws2 = (const float*)d_in[13];
  const float* Wn2 = (const float*)d_in[14];
  const float* b2  = (const float*)d_in[15];
  float* out = (float*)d_out;

  // ---- workspace layout (disjoint, ~162 MB) ----
  char* ws = (char*)d_ws;
  unsigned short* h1b = (unsigned short*)(ws + 0ull);           // 262144*256*2 = 134,217,728
  unsigned short* h2b = (unsigned short*)(ws + 134217728ull);   //  32768*256*2 =  16,777,216
  unsigned short* Wt0 = (unsigned short*)(ws + 150994944ull);   //     131,072
  unsigned short* Wt1 = (unsigned short*)(ws + 151126016ull);   //     262,144
  unsigned short* Wt2 = (unsigned short*)(ws + 151388160ull);   //     262,144
  int* cnt0 = (int*)(ws + 151650304ull);   // 1,048,576
  int* cnt1 = (int*)(ws + 152698880ull);   //   131,072
  int* cnt2 = (int*)(ws + 152829952ull);   //    32,768
  int* gctr = (int*)(ws + 152862720ull);   //       256
  int* off0 = (int*)(ws + 152862976ull);   // 1,048,576
  int* off1 = (int*)(ws + 153911552ull);   //   131,072
  int* off2 = (int*)(ws + 154042624ull);   //    32,768
  int* cur0 = (int*)(ws + 154075392ull);   // 1,048,576
  int* cur1 = (int*)(ws + 155123968ull);   //   131,072
  int* cur2 = (int*)(ws + 155255040ull);   //    32,768
  int* eidx0 = (int*)(ws + 155287808ull);  // 5,242,880
  int* eidx1 = (int*)(ws + 160530688ull);  // 1,310,720
  int* eidx2 = (int*)(ws + 161841408ull);  //   327,680

  // zero cnt0|cnt1|cnt2|gctr in one contiguous span [151650304, 152862976)
  hipMemsetAsync(ws + 151650304ull, 0, 1212672ull, stream);

  // ---- CSR builds (3 launches; weight prep folded into hist) ----
  hist3_prep_kernel<<<6720 + 1280, 256, 0, stream>>>(
      ed0, cnt0, ed1, cnt1, ed2, cnt2,
      Ws0, Wn0, Wt0, Ws1, Wn1, Wt1, Ws2, Wn2, Wt2);
  offsets3_kernel<<<cdiv_u(kN1 + kN2 + kN3, 256), 256, 0, stream>>>(
      cnt0, off0, cur0, cnt1, off1, cur1, cnt2, off2, cur2, gctr);
  build3_kernel<<<cdiv_u(kE0 + kE1 + kE2, 256), 256, 0, stream>>>(
      es0, ed0, cur0, eidx0, es1, ed1, cur1, eidx1, es2, ed2, cur2, eidx2);

  // ---- layer 0: fused gather+GEMM; self straight from x (fp32) ----
  sage_gemm<128, 128, true, true, true><<<kN1 / 64, 256, 0, stream>>>(
      x, 100, off0, cnt0, eidx0, x, Wt0, b0, h1b, 256);

  // ---- layer 1 ----
  sage_gemm<256, 256, false, true, true><<<kN2 / 64, 256, 0, stream>>>(
      h1b, 256, off1, cnt1, eidx1, h1b, Wt1, b1, h2b, 256);

  // ---- layer 2 ----
  sage_gemm<256, 256, false, false, false><<<kN3 / 64, 256, 0, stream>>>(
      h2b, 256, off2, cnt2, eidx2, h2b, Wt2, b2, out, 47);
}